// Round 1
// baseline (822.214 us; speedup 1.0000x reference)
//
#include <hip/hip_runtime.h>
#include <hip/hip_bf16.h>

#define N_NODES 50000
#define N_EDGES 800000
#define HID 128

// ---------------------------------------------------------------- utilities

__global__ void zero_k(int* __restrict__ p, int n) {
    int i = blockIdx.x * blockDim.x + threadIdx.x;
    if (i < n) p[i] = 0;
}

__global__ void count_k(const int* __restrict__ dst, int* __restrict__ cnt, int E) {
    int e = blockIdx.x * blockDim.x + threadIdx.x;
    if (e < E) atomicAdd(&cnt[dst[e]], 1);
}

// Single-block exclusive scan over n counts (n <= 1024*chunk).
// Writes offs[0..n] (offs[n]=total) and a mutable copy `cursor` for the fill pass.
__global__ __launch_bounds__(1024)
void scan_k(const int* __restrict__ cnt, int* __restrict__ offs,
            int* __restrict__ cursor, int n) {
    __shared__ int sh[1024];
    const int t = threadIdx.x;
    const int chunk = (n + 1023) / 1024;
    int beg = t * chunk;
    int end = beg + chunk; if (end > n) end = n;
    int s = 0;
    for (int i = beg; i < end; ++i) s += cnt[i];
    sh[t] = s;
    __syncthreads();
    // Hillis-Steele inclusive scan
    for (int off = 1; off < 1024; off <<= 1) {
        int v = (t >= off) ? sh[t - off] : 0;
        __syncthreads();
        sh[t] += v;
        __syncthreads();
    }
    int base = (t == 0) ? 0 : sh[t - 1];
    for (int i = beg; i < end; ++i) {
        offs[i] = base;
        cursor[i] = base;
        base += cnt[i];
    }
    if (t == 1023) offs[n] = sh[1023];
}

__global__ void fill_k(const int* __restrict__ src, const int* __restrict__ dst,
                       int* __restrict__ cursor, int* __restrict__ csr, int E) {
    int e = blockIdx.x * blockDim.x + threadIdx.x;
    if (e < E) {
        int p = atomicAdd(&cursor[dst[e]], 1);
        csr[p] = src[e];
    }
}

// ------------------------------------------------------------- aggregation
// z[node] = (1+eps[l]) * h[node] + sum_{s in neigh(node)} h[s]
// one 128-thread block per node, thread = feature
__global__ __launch_bounds__(128)
void agg_k(const float* __restrict__ h, const int* __restrict__ offs,
           const int* __restrict__ csr, const float* __restrict__ eps, int layer,
           float* __restrict__ z) {
    const int node = blockIdx.x;
    const int f = threadIdx.x;
    const int beg = offs[node];
    const int end = offs[node + 1];
    float acc = (1.0f + eps[layer]) * h[(size_t)node * HID + f];
    for (int j = beg; j < end; ++j) {
        int s = csr[j];
        acc += h[(size_t)s * HID + f];
    }
    z[(size_t)node * HID + f] = acc;
}

// ------------------------------------------------------------------- GEMM
// C[M x NCOL] = act(A[M x 128] @ W[128 x NCOL] + b), act = ReLU if RELU.
// In-place safe (C may alias A): each block stages its 64 rows to LDS first
// and only writes those same rows; one block owns all NCOL output columns.
// LDS = 34.8K (At, padded to 68 for bank-conflict-free transpose store and
// 16B-aligned float4 reads) + 32K (Ws) = 67.6 KB -> 2 blocks/CU.
template <int NCOL, bool RELU>
__global__ __launch_bounds__(256)
void gemm_k128(const float* __restrict__ A, const float* __restrict__ W,
               const float* __restrict__ b, float* __restrict__ C, int M) {
    __shared__ float At[128][68];   // At[k][r]
    __shared__ float Ws[128][64];   // Ws[k][c] for current 64-col half
    const int t = threadIdx.x;
    const int row0 = blockIdx.x * 64;

    // stage A tile transposed; coalesced global read, (k+r)%32 banks on write
    for (int i = 0; i < 32; ++i) {
        int idx = i * 256 + t;      // 0..8191 = 64 rows x 128 k
        int r = idx >> 7;
        int k = idx & 127;
        float v = 0.0f;
        int row = row0 + r;
        if (row < M) v = A[(size_t)row * 128 + k];
        At[k][r] = v;
    }

    constexpr int NHALF = (NCOL + 63) / 64;
    const int tx = t & 15;          // col quad
    const int ty = t >> 4;          // row quad

    for (int h = 0; h < NHALF; ++h) {
        __syncthreads();            // At staged / previous half's Ws reads done
        for (int i = 0; i < 16; ++i) {
            int idx = i * 512 + t * 2;          // 0..8191 = 128 k x 64 c, 2 at a time
            int k = idx >> 6;
            int c = idx & 63;
            Ws[k][c]     = W[k * NCOL + h * 64 + c];
            Ws[k][c + 1] = W[k * NCOL + h * 64 + c + 1];
        }
        __syncthreads();

        float acc[4][4];
        for (int i = 0; i < 4; ++i)
            for (int j = 0; j < 4; ++j) acc[i][j] = 0.0f;

#pragma unroll 8
        for (int k = 0; k < 128; ++k) {
            float4 a4 = *(const float4*)&At[k][ty * 4];
            float4 w4 = *(const float4*)&Ws[k][tx * 4];
            acc[0][0] += a4.x * w4.x; acc[0][1] += a4.x * w4.y;
            acc[0][2] += a4.x * w4.z; acc[0][3] += a4.x * w4.w;
            acc[1][0] += a4.y * w4.x; acc[1][1] += a4.y * w4.y;
            acc[1][2] += a4.y * w4.z; acc[1][3] += a4.y * w4.w;
            acc[2][0] += a4.z * w4.x; acc[2][1] += a4.z * w4.y;
            acc[2][2] += a4.z * w4.z; acc[2][3] += a4.z * w4.w;
            acc[3][0] += a4.w * w4.x; acc[3][1] += a4.w * w4.y;
            acc[3][2] += a4.w * w4.z; acc[3][3] += a4.w * w4.w;
        }

        const int c0 = h * 64 + tx * 4;
        float4 bb = *(const float4*)&b[c0];
        for (int r = 0; r < 4; ++r) {
            int row = row0 + ty * 4 + r;
            if (row < M) {
                float4 o;
                o.x = acc[r][0] + bb.x;
                o.y = acc[r][1] + bb.y;
                o.z = acc[r][2] + bb.z;
                o.w = acc[r][3] + bb.w;
                if (RELU) {
                    o.x = fmaxf(o.x, 0.0f); o.y = fmaxf(o.y, 0.0f);
                    o.z = fmaxf(o.z, 0.0f); o.w = fmaxf(o.w, 0.0f);
                }
                *(float4*)&C[(size_t)row * NCOL + c0] = o;
            }
        }
    }
}

// -------------------------------------------------------------- final head
// out[r][0..1] = hid[r][0..63] @ W2[64x2] + b2
__global__ __launch_bounds__(256)
void head2_k(const float* __restrict__ hid, const float* __restrict__ W2,
             const float* __restrict__ b2, float* __restrict__ out, int M) {
    int r = blockIdx.x * blockDim.x + threadIdx.x;
    if (r >= M) return;
    float a0 = b2[0], a1 = b2[1];
    const float* hrow = hid + (size_t)r * 64;
#pragma unroll
    for (int c = 0; c < 64; ++c) {
        float v = hrow[c];
        a0 += v * W2[c * 2 + 0];
        a1 += v * W2[c * 2 + 1];
    }
    out[(size_t)r * 2 + 0] = a0;
    out[(size_t)r * 2 + 1] = a1;
}

// ------------------------------------------------------------------ launch

extern "C" void kernel_launch(void* const* d_in, const int* in_sizes, int n_in,
                              void* d_out, int out_size, void* d_ws, size_t ws_size,
                              hipStream_t stream) {
    const float* x    = (const float*)d_in[0];
    const int*   ei   = (const int*)d_in[1];     // [2, E] int32 (harness ABI)
    const float* eps  = (const float*)d_in[2];   // [3]
    const float* W_a  = (const float*)d_in[3];   // [3,128,128]
    const float* b_a  = (const float*)d_in[4];   // [3,128]
    const float* W_b  = (const float*)d_in[5];
    const float* b_b  = (const float*)d_in[6];
    const float* W_h1 = (const float*)d_in[7];   // [128,64]
    const float* b_h1 = (const float*)d_in[8];   // [64]
    const float* W_h2 = (const float*)d_in[9];   // [64,2]
    const float* b_h2 = (const float*)d_in[10];  // [2]
    float* out = (float*)d_out;

    const int N = N_NODES, E = N_EDGES;
    const int* src = ei;
    const int* dst = ei + E;

    // workspace carve-up (all 256B-aligned)
    char* ws = (char*)d_ws;
    size_t off = 0;
    auto carve = [&](size_t bytes) {
        char* p = ws + off;
        off = (off + bytes + 255) & ~(size_t)255;
        return p;
    };
    float* bufA   = (float*)carve((size_t)N * HID * sizeof(float));
    float* bufB   = (float*)carve((size_t)N * HID * sizeof(float));
    int*   cnt    = (int*)carve((size_t)N * sizeof(int));
    int*   offs   = (int*)carve((size_t)(N + 1) * sizeof(int));
    int*   cursor = (int*)carve((size_t)N * sizeof(int));
    int*   csr    = (int*)carve((size_t)E * sizeof(int));
    (void)ws_size;

    // ---- CSR build (pull-based aggregation, no per-feature atomics)
    zero_k<<<(N + 255) / 256, 256, 0, stream>>>(cnt, N);
    count_k<<<(E + 255) / 256, 256, 0, stream>>>(dst, cnt, E);
    scan_k<<<1, 1024, 0, stream>>>(cnt, offs, cursor, N);
    fill_k<<<(E + 255) / 256, 256, 0, stream>>>(src, dst, cursor, csr, E);

    const int gemm_grid = (N + 63) / 64;

    // ---- layer 0: h = x
    agg_k<<<N, 128, 0, stream>>>(x, offs, csr, eps, 0, bufA);
    gemm_k128<128, true><<<gemm_grid, 256, 0, stream>>>(bufA, W_a + 0 * 128 * 128, b_a + 0 * 128, bufA, N);
    gemm_k128<128, true><<<gemm_grid, 256, 0, stream>>>(bufA, W_b + 0 * 128 * 128, b_b + 0 * 128, bufA, N);
    // ---- layer 1
    agg_k<<<N, 128, 0, stream>>>(bufA, offs, csr, eps, 1, bufB);
    gemm_k128<128, true><<<gemm_grid, 256, 0, stream>>>(bufB, W_a + 1 * 128 * 128, b_a + 1 * 128, bufB, N);
    gemm_k128<128, true><<<gemm_grid, 256, 0, stream>>>(bufB, W_b + 1 * 128 * 128, b_b + 1 * 128, bufB, N);
    // ---- layer 2
    agg_k<<<N, 128, 0, stream>>>(bufB, offs, csr, eps, 2, bufA);
    gemm_k128<128, true><<<gemm_grid, 256, 0, stream>>>(bufA, W_a + 2 * 128 * 128, b_a + 2 * 128, bufA, N);
    gemm_k128<128, true><<<gemm_grid, 256, 0, stream>>>(bufA, W_b + 2 * 128 * 128, b_b + 2 * 128, bufA, N);
    // ---- head
    gemm_k128<64, true><<<gemm_grid, 256, 0, stream>>>(bufA, W_h1, b_h1, bufB, N);
    head2_k<<<(N + 255) / 256, 256, 0, stream>>>(bufB, W_h2, b_h2, out, N);
}

// Round 2
// 724.073 us; speedup vs baseline: 1.1355x; 1.1355x over previous
//
#include <hip/hip_runtime.h>
#include <hip/hip_bf16.h>

#define N_NODES 50000
#define N_EDGES 800000
#define HID 128

// ---------------------------------------------------------------- utilities

__global__ void zero_k(int* __restrict__ p, int n) {
    int i = blockIdx.x * blockDim.x + threadIdx.x;
    if (i < n) p[i] = 0;
}

__global__ void count_k(const int* __restrict__ dst, int* __restrict__ cnt, int E) {
    int e = blockIdx.x * blockDim.x + threadIdx.x;
    if (e < E) atomicAdd(&cnt[dst[e]], 1);
}

// ---------------- 3-pass multi-block exclusive scan over n counts ----------
// Pass 1: per-block (1024 counts) sums. Pass 2: one-wave scan of block sums
// (B <= 64). Pass 3: block-local scan + apply block offset, int4 stores.

#define SCAN_CHUNK 1024   // counts per block (256 thr x 4)

__global__ __launch_bounds__(256)
void scan1_k(const int* __restrict__ cnt, int* __restrict__ bsum, int n) {
    const int t = threadIdx.x;
    const int base = blockIdx.x * SCAN_CHUNK + t * 4;
    int4 v = {0, 0, 0, 0};
    if (base + 3 < n) v = *(const int4*)&cnt[base];
    else {
        if (base + 0 < n) v.x = cnt[base + 0];
        if (base + 1 < n) v.y = cnt[base + 1];
        if (base + 2 < n) v.z = cnt[base + 2];
        if (base + 3 < n) v.w = cnt[base + 3];
    }
    int s = v.x + v.y + v.z + v.w;
    __shared__ int sh[256];
    sh[t] = s;
    __syncthreads();
    for (int o = 128; o > 0; o >>= 1) {
        if (t < o) sh[t] += sh[t + o];
        __syncthreads();
    }
    if (t == 0) bsum[blockIdx.x] = sh[0];
}

// One wave: exclusive-scan B (<=64) block sums in place; offs[n] = total.
__global__ __launch_bounds__(64)
void scan2_k(int* __restrict__ bsum, int* __restrict__ offs, int B, int n) {
    const int t = threadIdx.x;
    int own = (t < B) ? bsum[t] : 0;
    int v = own;
    for (int o = 1; o < 64; o <<= 1) {
        int u = __shfl_up(v, o, 64);
        if (t >= o) v += u;
    }
    if (t < B) bsum[t] = v - own;   // exclusive prefix
    if (t == 63) offs[n] = v;       // grand total
}

__global__ __launch_bounds__(256)
void scan3_k(const int* __restrict__ cnt, const int* __restrict__ bsum,
             int* __restrict__ offs, int* __restrict__ cursor, int n) {
    const int t = threadIdx.x;
    const int base = blockIdx.x * SCAN_CHUNK + t * 4;
    int4 v = {0, 0, 0, 0};
    if (base + 3 < n) v = *(const int4*)&cnt[base];
    else {
        if (base + 0 < n) v.x = cnt[base + 0];
        if (base + 1 < n) v.y = cnt[base + 1];
        if (base + 2 < n) v.z = cnt[base + 2];
        if (base + 3 < n) v.w = cnt[base + 3];
    }
    int s = v.x + v.y + v.z + v.w;
    __shared__ int sh[256];
    sh[t] = s;
    __syncthreads();
    // Hillis-Steele inclusive scan over 256 thread sums
    for (int o = 1; o < 256; o <<= 1) {
        int u = (t >= o) ? sh[t - o] : 0;
        __syncthreads();
        sh[t] += u;
        __syncthreads();
    }
    int excl = ((t == 0) ? 0 : sh[t - 1]) + bsum[blockIdx.x];
    int4 o4;
    o4.x = excl;
    o4.y = o4.x + v.x;
    o4.z = o4.y + v.y;
    o4.w = o4.z + v.z;
    if (base + 3 < n) {
        *(int4*)&offs[base] = o4;
        *(int4*)&cursor[base] = o4;
    } else {
        if (base + 0 < n) { offs[base + 0] = o4.x; cursor[base + 0] = o4.x; }
        if (base + 1 < n) { offs[base + 1] = o4.y; cursor[base + 1] = o4.y; }
        if (base + 2 < n) { offs[base + 2] = o4.z; cursor[base + 2] = o4.z; }
        if (base + 3 < n) { offs[base + 3] = o4.w; cursor[base + 3] = o4.w; }
    }
}

__global__ void fill_k(const int* __restrict__ src, const int* __restrict__ dst,
                       int* __restrict__ cursor, int* __restrict__ csr, int E) {
    int e = blockIdx.x * blockDim.x + threadIdx.x;
    if (e < E) {
        int p = atomicAdd(&cursor[dst[e]], 1);
        csr[p] = src[e];
    }
}

// ------------------------------------------------------------- aggregation
// z[node] = (1+eps[l]) * h[node] + sum_{s in neigh(node)} h[s]
// one 128-thread block per node, thread = feature
__global__ __launch_bounds__(128)
void agg_k(const float* __restrict__ h, const int* __restrict__ offs,
           const int* __restrict__ csr, const float* __restrict__ eps, int layer,
           float* __restrict__ z) {
    const int node = blockIdx.x;
    const int f = threadIdx.x;
    const int beg = offs[node];
    const int end = offs[node + 1];
    float acc = (1.0f + eps[layer]) * h[(size_t)node * HID + f];
    for (int j = beg; j < end; ++j) {
        int s = csr[j];
        acc += h[(size_t)s * HID + f];
    }
    z[(size_t)node * HID + f] = acc;
}

// ------------------------------------------------------------------- GEMM
// C[M x NCOL] = act(A[M x 128] @ W[128 x NCOL] + b), act = ReLU if RELU.
// In-place safe (C may alias A): each block stages its 64 rows to LDS first
// and only writes those same rows; one block owns all NCOL output columns.
template <int NCOL, bool RELU>
__global__ __launch_bounds__(256)
void gemm_k128(const float* __restrict__ A, const float* __restrict__ W,
               const float* __restrict__ b, float* __restrict__ C, int M) {
    __shared__ float At[128][68];   // At[k][r]
    __shared__ float Ws[128][64];   // Ws[k][c] for current 64-col half
    const int t = threadIdx.x;
    const int row0 = blockIdx.x * 64;

    // stage A tile transposed; coalesced global read, (k+r)%32 banks on write
    for (int i = 0; i < 32; ++i) {
        int idx = i * 256 + t;      // 0..8191 = 64 rows x 128 k
        int r = idx >> 7;
        int k = idx & 127;
        float v = 0.0f;
        int row = row0 + r;
        if (row < M) v = A[(size_t)row * 128 + k];
        At[k][r] = v;
    }

    constexpr int NHALF = (NCOL + 63) / 64;
    const int tx = t & 15;          // col quad
    const int ty = t >> 4;          // row quad

    for (int h = 0; h < NHALF; ++h) {
        __syncthreads();            // At staged / previous half's Ws reads done
        for (int i = 0; i < 16; ++i) {
            int idx = i * 512 + t * 2;          // 0..8191 = 128 k x 64 c, 2 at a time
            int k = idx >> 6;
            int c = idx & 63;
            Ws[k][c]     = W[k * NCOL + h * 64 + c];
            Ws[k][c + 1] = W[k * NCOL + h * 64 + c + 1];
        }
        __syncthreads();

        float acc[4][4];
        for (int i = 0; i < 4; ++i)
            for (int j = 0; j < 4; ++j) acc[i][j] = 0.0f;

#pragma unroll 8
        for (int k = 0; k < 128; ++k) {
            float4 a4 = *(const float4*)&At[k][ty * 4];
            float4 w4 = *(const float4*)&Ws[k][tx * 4];
            acc[0][0] += a4.x * w4.x; acc[0][1] += a4.x * w4.y;
            acc[0][2] += a4.x * w4.z; acc[0][3] += a4.x * w4.w;
            acc[1][0] += a4.y * w4.x; acc[1][1] += a4.y * w4.y;
            acc[1][2] += a4.y * w4.z; acc[1][3] += a4.y * w4.w;
            acc[2][0] += a4.z * w4.x; acc[2][1] += a4.z * w4.y;
            acc[2][2] += a4.z * w4.z; acc[2][3] += a4.z * w4.w;
            acc[3][0] += a4.w * w4.x; acc[3][1] += a4.w * w4.y;
            acc[3][2] += a4.w * w4.z; acc[3][3] += a4.w * w4.w;
        }

        const int c0 = h * 64 + tx * 4;
        float4 bb = *(const float4*)&b[c0];
        for (int r = 0; r < 4; ++r) {
            int row = row0 + ty * 4 + r;
            if (row < M) {
                float4 o;
                o.x = acc[r][0] + bb.x;
                o.y = acc[r][1] + bb.y;
                o.z = acc[r][2] + bb.z;
                o.w = acc[r][3] + bb.w;
                if (RELU) {
                    o.x = fmaxf(o.x, 0.0f); o.y = fmaxf(o.y, 0.0f);
                    o.z = fmaxf(o.z, 0.0f); o.w = fmaxf(o.w, 0.0f);
                }
                *(float4*)&C[(size_t)row * NCOL + c0] = o;
            }
        }
    }
}

// -------------------------------------------------------------- final head
// out[r][0..1] = hid[r][0..63] @ W2[64x2] + b2
__global__ __launch_bounds__(256)
void head2_k(const float* __restrict__ hid, const float* __restrict__ W2,
             const float* __restrict__ b2, float* __restrict__ out, int M) {
    int r = blockIdx.x * blockDim.x + threadIdx.x;
    if (r >= M) return;
    float a0 = b2[0], a1 = b2[1];
    const float* hrow = hid + (size_t)r * 64;
#pragma unroll
    for (int c = 0; c < 64; ++c) {
        float v = hrow[c];
        a0 += v * W2[c * 2 + 0];
        a1 += v * W2[c * 2 + 1];
    }
    out[(size_t)r * 2 + 0] = a0;
    out[(size_t)r * 2 + 1] = a1;
}

// ------------------------------------------------------------------ launch

extern "C" void kernel_launch(void* const* d_in, const int* in_sizes, int n_in,
                              void* d_out, int out_size, void* d_ws, size_t ws_size,
                              hipStream_t stream) {
    const float* x    = (const float*)d_in[0];
    const int*   ei   = (const int*)d_in[1];     // [2, E] int32 (harness ABI)
    const float* eps  = (const float*)d_in[2];   // [3]
    const float* W_a  = (const float*)d_in[3];   // [3,128,128]
    const float* b_a  = (const float*)d_in[4];   // [3,128]
    const float* W_b  = (const float*)d_in[5];
    const float* b_b  = (const float*)d_in[6];
    const float* W_h1 = (const float*)d_in[7];   // [128,64]
    const float* b_h1 = (const float*)d_in[8];   // [64]
    const float* W_h2 = (const float*)d_in[9];   // [64,2]
    const float* b_h2 = (const float*)d_in[10];  // [2]
    float* out = (float*)d_out;

    const int N = N_NODES, E = N_EDGES;
    const int* src = ei;
    const int* dst = ei + E;

    // workspace carve-up (all 256B-aligned)
    char* ws = (char*)d_ws;
    size_t off = 0;
    auto carve = [&](size_t bytes) {
        char* p = ws + off;
        off = (off + bytes + 255) & ~(size_t)255;
        return p;
    };
    float* bufA   = (float*)carve((size_t)N * HID * sizeof(float));
    float* bufB   = (float*)carve((size_t)N * HID * sizeof(float));
    int*   cnt    = (int*)carve((size_t)N * sizeof(int));
    int*   offs   = (int*)carve((size_t)(N + 1) * sizeof(int));
    int*   cursor = (int*)carve((size_t)N * sizeof(int));
    int*   csr    = (int*)carve((size_t)E * sizeof(int));
    int*   bsum   = (int*)carve(64 * sizeof(int));
    (void)ws_size;

    // ---- CSR build (pull-based aggregation, no per-feature atomics)
    zero_k<<<(N + 255) / 256, 256, 0, stream>>>(cnt, N);
    count_k<<<(E + 255) / 256, 256, 0, stream>>>(dst, cnt, E);
    const int SB = (N + SCAN_CHUNK - 1) / SCAN_CHUNK;   // 49 blocks
    scan1_k<<<SB, 256, 0, stream>>>(cnt, bsum, N);
    scan2_k<<<1, 64, 0, stream>>>(bsum, offs, SB, N);
    scan3_k<<<SB, 256, 0, stream>>>(cnt, bsum, offs, cursor, N);
    fill_k<<<(E + 255) / 256, 256, 0, stream>>>(src, dst, cursor, csr, E);

    const int gemm_grid = (N + 63) / 64;

    // ---- layer 0: h = x
    agg_k<<<N, 128, 0, stream>>>(x, offs, csr, eps, 0, bufA);
    gemm_k128<128, true><<<gemm_grid, 256, 0, stream>>>(bufA, W_a + 0 * 128 * 128, b_a + 0 * 128, bufA, N);
    gemm_k128<128, true><<<gemm_grid, 256, 0, stream>>>(bufA, W_b + 0 * 128 * 128, b_b + 0 * 128, bufA, N);
    // ---- layer 1
    agg_k<<<N, 128, 0, stream>>>(bufA, offs, csr, eps, 1, bufB);
    gemm_k128<128, true><<<gemm_grid, 256, 0, stream>>>(bufB, W_a + 1 * 128 * 128, b_a + 1 * 128, bufB, N);
    gemm_k128<128, true><<<gemm_grid, 256, 0, stream>>>(bufB, W_b + 1 * 128 * 128, b_b + 1 * 128, bufB, N);
    // ---- layer 2
    agg_k<<<N, 128, 0, stream>>>(bufB, offs, csr, eps, 2, bufA);
    gemm_k128<128, true><<<gemm_grid, 256, 0, stream>>>(bufA, W_a + 2 * 128 * 128, b_a + 2 * 128, bufA, N);
    gemm_k128<128, true><<<gemm_grid, 256, 0, stream>>>(bufA, W_b + 2 * 128 * 128, b_b + 2 * 128, bufA, N);
    // ---- head
    gemm_k128<64, true><<<gemm_grid, 256, 0, stream>>>(bufA, W_h1, b_h1, bufB, N);
    head2_k<<<(N + 255) / 256, 256, 0, stream>>>(bufB, W_h2, b_h2, out, N);
}

// Round 3
// 464.460 us; speedup vs baseline: 1.7703x; 1.5590x over previous
//
#include <hip/hip_runtime.h>
#include <hip/hip_bf16.h>

#define N_NODES 50000
#define N_EDGES 800000
#define HID 128

typedef __attribute__((ext_vector_type(8))) short short8;     // 8 bf16 (4 VGPR)
typedef __attribute__((ext_vector_type(4))) float f32x4;      // MFMA acc
typedef __attribute__((ext_vector_type(4))) unsigned short us4;

__device__ __forceinline__ unsigned short f2bf(float v) {
    union { float f; unsigned u; } x; x.f = v;
    unsigned r = x.u + 0x7fff + ((x.u >> 16) & 1);   // RTN-even
    return (unsigned short)(r >> 16);
}
__device__ __forceinline__ float bf2f(unsigned short b) {
    union { unsigned u; float f; } x; x.u = ((unsigned)b) << 16;
    return x.f;
}

// ---------------------------------------------------------------- utilities

__global__ void zero_k(int* __restrict__ p, int n) {
    int i = blockIdx.x * blockDim.x + threadIdx.x;
    if (i < n) p[i] = 0;
}

__global__ void count_k(const int* __restrict__ dst, int* __restrict__ cnt, int E) {
    int e = blockIdx.x * blockDim.x + threadIdx.x;
    if (e < E) atomicAdd(&cnt[dst[e]], 1);
}

// ---------------- 3-pass multi-block exclusive scan over n counts ----------
#define SCAN_CHUNK 1024

__global__ __launch_bounds__(256)
void scan1_k(const int* __restrict__ cnt, int* __restrict__ bsum, int n) {
    const int t = threadIdx.x;
    const int base = blockIdx.x * SCAN_CHUNK + t * 4;
    int4 v = {0, 0, 0, 0};
    if (base + 3 < n) v = *(const int4*)&cnt[base];
    else {
        if (base + 0 < n) v.x = cnt[base + 0];
        if (base + 1 < n) v.y = cnt[base + 1];
        if (base + 2 < n) v.z = cnt[base + 2];
        if (base + 3 < n) v.w = cnt[base + 3];
    }
    int s = v.x + v.y + v.z + v.w;
    __shared__ int sh[256];
    sh[t] = s;
    __syncthreads();
    for (int o = 128; o > 0; o >>= 1) {
        if (t < o) sh[t] += sh[t + o];
        __syncthreads();
    }
    if (t == 0) bsum[blockIdx.x] = sh[0];
}

__global__ __launch_bounds__(64)
void scan2_k(int* __restrict__ bsum, int* __restrict__ offs, int B, int n) {
    const int t = threadIdx.x;
    int own = (t < B) ? bsum[t] : 0;
    int v = own;
    for (int o = 1; o < 64; o <<= 1) {
        int u = __shfl_up(v, o, 64);
        if (t >= o) v += u;
    }
    if (t < B) bsum[t] = v - own;
    if (t == 63) offs[n] = v;
}

__global__ __launch_bounds__(256)
void scan3_k(const int* __restrict__ cnt, const int* __restrict__ bsum,
             int* __restrict__ offs, int* __restrict__ cursor, int n) {
    const int t = threadIdx.x;
    const int base = blockIdx.x * SCAN_CHUNK + t * 4;
    int4 v = {0, 0, 0, 0};
    if (base + 3 < n) v = *(const int4*)&cnt[base];
    else {
        if (base + 0 < n) v.x = cnt[base + 0];
        if (base + 1 < n) v.y = cnt[base + 1];
        if (base + 2 < n) v.z = cnt[base + 2];
        if (base + 3 < n) v.w = cnt[base + 3];
    }
    int s = v.x + v.y + v.z + v.w;
    __shared__ int sh[256];
    sh[t] = s;
    __syncthreads();
    for (int o = 1; o < 256; o <<= 1) {
        int u = (t >= o) ? sh[t - o] : 0;
        __syncthreads();
        sh[t] += u;
        __syncthreads();
    }
    int excl = ((t == 0) ? 0 : sh[t - 1]) + bsum[blockIdx.x];
    int4 o4;
    o4.x = excl;
    o4.y = o4.x + v.x;
    o4.z = o4.y + v.y;
    o4.w = o4.z + v.z;
    if (base + 3 < n) {
        *(int4*)&offs[base] = o4;
        *(int4*)&cursor[base] = o4;
    } else {
        if (base + 0 < n) { offs[base + 0] = o4.x; cursor[base + 0] = o4.x; }
        if (base + 1 < n) { offs[base + 1] = o4.y; cursor[base + 1] = o4.y; }
        if (base + 2 < n) { offs[base + 2] = o4.z; cursor[base + 2] = o4.z; }
        if (base + 3 < n) { offs[base + 3] = o4.w; cursor[base + 3] = o4.w; }
    }
}

__global__ void fill_k(const int* __restrict__ src, const int* __restrict__ dst,
                       int* __restrict__ cursor, int* __restrict__ csr, int E) {
    int e = blockIdx.x * blockDim.x + threadIdx.x;
    if (e < E) {
        int p = atomicAdd(&cursor[dst[e]], 1);
        csr[p] = src[e];
    }
}

// ------------------------------------------------------------- aggregation
// 32 lanes per node (float4/thread), 8 nodes per 256-block.
// Neighbor loop unrolled x4 with independent accumulators for load ILP.
__global__ __launch_bounds__(256)
void agg_k(const float* __restrict__ h, const int* __restrict__ offs,
           const int* __restrict__ csr, const float* __restrict__ eps, int layer,
           float* __restrict__ z) {
    const int lane = threadIdx.x & 31;
    const int node = blockIdx.x * 8 + (threadIdx.x >> 5);
    if (node >= N_NODES) return;
    const float4* __restrict__ h4 = (const float4*)h;
    const int beg = offs[node];
    const int end = offs[node + 1];
    float4 a0 = {0,0,0,0}, a1 = {0,0,0,0}, a2 = {0,0,0,0}, a3 = {0,0,0,0};
    int j = beg;
    for (; j + 4 <= end; j += 4) {
        int s0 = csr[j], s1 = csr[j+1], s2 = csr[j+2], s3 = csr[j+3];
        float4 v0 = h4[(size_t)s0 * 32 + lane];
        float4 v1 = h4[(size_t)s1 * 32 + lane];
        float4 v2 = h4[(size_t)s2 * 32 + lane];
        float4 v3 = h4[(size_t)s3 * 32 + lane];
        a0.x += v0.x; a0.y += v0.y; a0.z += v0.z; a0.w += v0.w;
        a1.x += v1.x; a1.y += v1.y; a1.z += v1.z; a1.w += v1.w;
        a2.x += v2.x; a2.y += v2.y; a2.z += v2.z; a2.w += v2.w;
        a3.x += v3.x; a3.y += v3.y; a3.z += v3.z; a3.w += v3.w;
    }
    for (; j < end; ++j) {
        float4 v = h4[(size_t)csr[j] * 32 + lane];
        a0.x += v.x; a0.y += v.y; a0.z += v.z; a0.w += v.w;
    }
    const float sc = 1.0f + eps[layer];
    float4 self = h4[(size_t)node * 32 + lane];
    float4 o;
    o.x = sc * self.x + ((a0.x + a1.x) + (a2.x + a3.x));
    o.y = sc * self.y + ((a0.y + a1.y) + (a2.y + a3.y));
    o.z = sc * self.z + ((a0.z + a1.z) + (a2.z + a3.z));
    o.w = sc * self.w + ((a0.w + a1.w) + (a2.w + a3.w));
    ((float4*)z)[(size_t)node * 32 + lane] = o;
}

// ------------------------------------------- weight pre-split (bf16 hi/lo)
// Converts all layer weights to transposed bf16 hi/lo: Wt[n][k], slot stride
// 16384 elems. Slots: 2l = W_a[l], 2l+1 = W_b[l] (l=0..2), 6 = W_h1.
__global__ __launch_bounds__(256)
void wcvt_k(const float* __restrict__ Wa, const float* __restrict__ Wb,
            const float* __restrict__ Wh1,
            unsigned short* __restrict__ whi, unsigned short* __restrict__ wlo) {
    int id = blockIdx.x * 256 + threadIdx.x;
    float v; int dst;
    if (id < 49152) {                      // 3 x 128x128 W_a
        int l = id >> 14, e = id & 16383;
        v = Wa[id];
        int n = e & 127, k = e >> 7;
        dst = (2 * l) * 16384 + n * 128 + k;
    } else if (id < 98304) {               // 3 x 128x128 W_b
        int id2 = id - 49152;
        int l = id2 >> 14, e = id2 & 16383;
        v = Wb[id2];
        int n = e & 127, k = e >> 7;
        dst = (2 * l + 1) * 16384 + n * 128 + k;
    } else if (id < 106496) {              // 128x64 W_h1
        int e = id - 98304;
        v = Wh1[e];
        int n = e & 63, k = e >> 6;
        dst = 6 * 16384 + n * 128 + k;
    } else return;
    unsigned short hi = f2bf(v);
    whi[dst] = hi;
    wlo[dst] = f2bf(v - bf2f(hi));
}

// ----------------------------------------------------- split-bf16 MFMA GEMM
// C[M x NCOL] = act(A[M x 128] @ W[128 x NCOL] + b) with A,W split into
// bf16 hi+lo; 3 MFMA products (hi*hi, hi*lo, lo*hi) give ~fp32 accuracy.
// Block = 256 thr = 4 waves, 64 rows x NCOL cols. Wave w owns cols
// [w*NCOL/4, +NCOL/4). W frags live in registers; A tile staged to LDS as
// bf16 hi/lo (row stride 136 -> 2-way-free bank pattern on b128 reads).
// In-place safe: block stages its rows before writing only those rows.
template <int NCOL, bool RELU>
__global__ __launch_bounds__(256)
void gemm_mfma_k(const float* __restrict__ A,
                 const unsigned short* __restrict__ Wthi,
                 const unsigned short* __restrict__ Wtlo,
                 const float* __restrict__ b, float* __restrict__ C, int M) {
    __shared__ unsigned short Ahi[64 * 136];
    __shared__ unsigned short Alo[64 * 136];
    const int t = threadIdx.x;
    const int row0 = blockIdx.x * 64;

    // ---- stage A -> LDS bf16 hi/lo
    for (int i = 0; i < 8; ++i) {
        int q = i * 256 + t;          // 2048 float4 groups = 64 rows x 32
        int r = q >> 5;
        int c4 = q & 31;
        float4 v = {0, 0, 0, 0};
        int row = row0 + r;
        if (row < M) v = *(const float4*)&A[(size_t)row * 128 + c4 * 4];
        us4 hi, lo;
        hi.x = f2bf(v.x); lo.x = f2bf(v.x - bf2f(hi.x));
        hi.y = f2bf(v.y); lo.y = f2bf(v.y - bf2f(hi.y));
        hi.z = f2bf(v.z); lo.z = f2bf(v.z - bf2f(hi.z));
        hi.w = f2bf(v.w); lo.w = f2bf(v.w - bf2f(hi.w));
        *(us4*)&Ahi[r * 136 + c4 * 4] = hi;
        *(us4*)&Alo[r * 136 + c4 * 4] = lo;
    }

    // ---- W fragments into registers (L2-hot, reused over 64 rows)
    constexpr int CPW = NCOL / 64;            // col-tiles per wave (2 or 1)
    const int wave = t >> 6;
    const int lane = t & 63;
    const int m = lane & 15;
    const int quad = lane >> 4;               // 0..3
    const int colbase = wave * (NCOL / 4);
    short8 whi[CPW][4], wlo[CPW][4];
    for (int ct = 0; ct < CPW; ++ct) {
        int n = colbase + ct * 16 + m;
        for (int ks = 0; ks < 4; ++ks) {
            whi[ct][ks] = *(const short8*)&Wthi[n * 128 + ks * 32 + quad * 8];
            wlo[ct][ks] = *(const short8*)&Wtlo[n * 128 + ks * 32 + quad * 8];
        }
    }
    __syncthreads();

    // ---- main: 4 row-strips of 16, K = 4 steps of 32
    f32x4 acc[4][CPW];
    for (int s = 0; s < 4; ++s)
        for (int ct = 0; ct < CPW; ++ct) acc[s][ct] = (f32x4){0, 0, 0, 0};

    for (int s = 0; s < 4; ++s) {
        const int r = s * 16 + m;
        for (int ks = 0; ks < 4; ++ks) {
            short8 ahi = *(const short8*)&Ahi[r * 136 + ks * 32 + quad * 8];
            short8 alo = *(const short8*)&Alo[r * 136 + ks * 32 + quad * 8];
            for (int ct = 0; ct < CPW; ++ct) {
                acc[s][ct] = __builtin_amdgcn_mfma_f32_16x16x32_bf16(ahi, whi[ct][ks], acc[s][ct], 0, 0, 0);
                acc[s][ct] = __builtin_amdgcn_mfma_f32_16x16x32_bf16(ahi, wlo[ct][ks], acc[s][ct], 0, 0, 0);
                acc[s][ct] = __builtin_amdgcn_mfma_f32_16x16x32_bf16(alo, whi[ct][ks], acc[s][ct], 0, 0, 0);
            }
        }
    }

    // ---- epilogue: bias + ReLU, fp32 store
    for (int s = 0; s < 4; ++s) {
        for (int ct = 0; ct < CPW; ++ct) {
            int col = colbase + ct * 16 + m;          // D col = lane&15
            float bb = b[col];
            for (int i = 0; i < 4; ++i) {
                int row = row0 + s * 16 + quad * 4 + i;   // D row = quad*4+reg
                if (row < M) {
                    float o = acc[s][ct][i] + bb;
                    if (RELU) o = fmaxf(o, 0.0f);
                    C[(size_t)row * NCOL + col] = o;
                }
            }
        }
    }
}

// -------------------------------------------------------------- final head
__global__ __launch_bounds__(256)
void head2_k(const float* __restrict__ hid, const float* __restrict__ W2,
             const float* __restrict__ b2, float* __restrict__ out, int M) {
    int r = blockIdx.x * blockDim.x + threadIdx.x;
    if (r >= M) return;
    float a0 = b2[0], a1 = b2[1];
    const float* hrow = hid + (size_t)r * 64;
#pragma unroll
    for (int c = 0; c < 64; ++c) {
        float v = hrow[c];
        a0 += v * W2[c * 2 + 0];
        a1 += v * W2[c * 2 + 1];
    }
    out[(size_t)r * 2 + 0] = a0;
    out[(size_t)r * 2 + 1] = a1;
}

// ------------------------------------------------------------------ launch

extern "C" void kernel_launch(void* const* d_in, const int* in_sizes, int n_in,
                              void* d_out, int out_size, void* d_ws, size_t ws_size,
                              hipStream_t stream) {
    const float* x    = (const float*)d_in[0];
    const int*   ei   = (const int*)d_in[1];
    const float* eps  = (const float*)d_in[2];
    const float* W_a  = (const float*)d_in[3];
    const float* b_a  = (const float*)d_in[4];
    const float* W_b  = (const float*)d_in[5];
    const float* b_b  = (const float*)d_in[6];
    const float* W_h1 = (const float*)d_in[7];
    const float* b_h1 = (const float*)d_in[8];
    const float* W_h2 = (const float*)d_in[9];
    const float* b_h2 = (const float*)d_in[10];
    float* out = (float*)d_out;

    const int N = N_NODES, E = N_EDGES;
    const int* src = ei;
    const int* dst = ei + E;

    char* ws = (char*)d_ws;
    size_t off = 0;
    auto carve = [&](size_t bytes) {
        char* p = ws + off;
        off = (off + bytes + 255) & ~(size_t)255;
        return p;
    };
    float* bufA   = (float*)carve((size_t)N * HID * sizeof(float));
    float* bufB   = (float*)carve((size_t)N * HID * sizeof(float));
    int*   cnt    = (int*)carve((size_t)N * sizeof(int));
    int*   offs   = (int*)carve((size_t)(N + 1) * sizeof(int));
    int*   cursor = (int*)carve((size_t)N * sizeof(int));
    int*   csr    = (int*)carve((size_t)E * sizeof(int));
    int*   bsum   = (int*)carve(64 * sizeof(int));
    unsigned short* whi = (unsigned short*)carve(7 * 16384 * sizeof(unsigned short));
    unsigned short* wlo = (unsigned short*)carve(7 * 16384 * sizeof(unsigned short));
    (void)ws_size;

    // ---- CSR build
    zero_k<<<(N + 255) / 256, 256, 0, stream>>>(cnt, N);
    count_k<<<(E + 255) / 256, 256, 0, stream>>>(dst, cnt, E);
    const int SB = (N + SCAN_CHUNK - 1) / SCAN_CHUNK;
    scan1_k<<<SB, 256, 0, stream>>>(cnt, bsum, N);
    scan2_k<<<1, 64, 0, stream>>>(bsum, offs, SB, N);
    scan3_k<<<SB, 256, 0, stream>>>(cnt, bsum, offs, cursor, N);
    fill_k<<<(E + 255) / 256, 256, 0, stream>>>(src, dst, cursor, csr, E);

    // ---- weight split/transpose
    wcvt_k<<<(106496 + 255) / 256, 256, 0, stream>>>(W_a, W_b, W_h1, whi, wlo);

    const int agg_grid  = (N + 7) / 8;
    const int gemm_grid = (N + 63) / 64;
    #define WSLOT(s) (whi + (s) * 16384), (wlo + (s) * 16384)

    // ---- layer 0
    agg_k<<<agg_grid, 256, 0, stream>>>(x, offs, csr, eps, 0, bufA);
    gemm_mfma_k<128, true><<<gemm_grid, 256, 0, stream>>>(bufA, WSLOT(0), b_a + 0 * 128, bufA, N);
    gemm_mfma_k<128, true><<<gemm_grid, 256, 0, stream>>>(bufA, WSLOT(1), b_b + 0 * 128, bufA, N);
    // ---- layer 1
    agg_k<<<agg_grid, 256, 0, stream>>>(bufA, offs, csr, eps, 1, bufB);
    gemm_mfma_k<128, true><<<gemm_grid, 256, 0, stream>>>(bufB, WSLOT(2), b_a + 1 * 128, bufB, N);
    gemm_mfma_k<128, true><<<gemm_grid, 256, 0, stream>>>(bufB, WSLOT(3), b_b + 1 * 128, bufB, N);
    // ---- layer 2
    agg_k<<<agg_grid, 256, 0, stream>>>(bufB, offs, csr, eps, 2, bufA);
    gemm_mfma_k<128, true><<<gemm_grid, 256, 0, stream>>>(bufA, WSLOT(4), b_a + 2 * 128, bufA, N);
    gemm_mfma_k<128, true><<<gemm_grid, 256, 0, stream>>>(bufA, WSLOT(5), b_b + 2 * 128, bufA, N);
    // ---- head
    gemm_mfma_k<64, true><<<gemm_grid, 256, 0, stream>>>(bufA, WSLOT(6), b_h1, bufB, N);
    head2_k<<<(N + 255) / 256, 256, 0, stream>>>(bufB, W_h2, b_h2, out, N);
}

// Round 4
// 451.305 us; speedup vs baseline: 1.8219x; 1.0291x over previous
//
#include <hip/hip_runtime.h>
#include <hip/hip_bf16.h>

#define N_NODES 50000
#define N_EDGES 800000
#define HID 128

typedef __attribute__((ext_vector_type(8))) short short8;     // 8 bf16 (4 VGPR)
typedef __attribute__((ext_vector_type(4))) float f32x4;      // MFMA acc
typedef __attribute__((ext_vector_type(4))) unsigned short us4;

__device__ __forceinline__ unsigned short f2bf(float v) {
    union { float f; unsigned u; } x; x.f = v;
    unsigned r = x.u + 0x7fff + ((x.u >> 16) & 1);   // RTN-even
    return (unsigned short)(r >> 16);
}
__device__ __forceinline__ float bf2f(unsigned short b) {
    union { unsigned u; float f; } x; x.u = ((unsigned)b) << 16;
    return x.f;
}

// ---------------------------------------------------------------- utilities

__global__ void zero_k(int* __restrict__ p, int n) {
    int i = blockIdx.x * blockDim.x + threadIdx.x;
    if (i < n) p[i] = 0;
}

__global__ void count_k(const int* __restrict__ dst, int* __restrict__ cnt, int E) {
    int e = blockIdx.x * blockDim.x + threadIdx.x;
    if (e < E) atomicAdd(&cnt[dst[e]], 1);
}

// ---------------- 3-pass multi-block exclusive scan over n counts ----------
#define SCAN_CHUNK 1024

__global__ __launch_bounds__(256)
void scan1_k(const int* __restrict__ cnt, int* __restrict__ bsum, int n) {
    const int t = threadIdx.x;
    const int base = blockIdx.x * SCAN_CHUNK + t * 4;
    int4 v = {0, 0, 0, 0};
    if (base + 3 < n) v = *(const int4*)&cnt[base];
    else {
        if (base + 0 < n) v.x = cnt[base + 0];
        if (base + 1 < n) v.y = cnt[base + 1];
        if (base + 2 < n) v.z = cnt[base + 2];
        if (base + 3 < n) v.w = cnt[base + 3];
    }
    int s = v.x + v.y + v.z + v.w;
    __shared__ int sh[256];
    sh[t] = s;
    __syncthreads();
    for (int o = 128; o > 0; o >>= 1) {
        if (t < o) sh[t] += sh[t + o];
        __syncthreads();
    }
    if (t == 0) bsum[blockIdx.x] = sh[0];
}

__global__ __launch_bounds__(64)
void scan2_k(int* __restrict__ bsum, int* __restrict__ offs, int B, int n) {
    const int t = threadIdx.x;
    int own = (t < B) ? bsum[t] : 0;
    int v = own;
    for (int o = 1; o < 64; o <<= 1) {
        int u = __shfl_up(v, o, 64);
        if (t >= o) v += u;
    }
    if (t < B) bsum[t] = v - own;
    if (t == 63) offs[n] = v;
}

__global__ __launch_bounds__(256)
void scan3_k(const int* __restrict__ cnt, const int* __restrict__ bsum,
             int* __restrict__ offs, int* __restrict__ cursor, int n) {
    const int t = threadIdx.x;
    const int base = blockIdx.x * SCAN_CHUNK + t * 4;
    int4 v = {0, 0, 0, 0};
    if (base + 3 < n) v = *(const int4*)&cnt[base];
    else {
        if (base + 0 < n) v.x = cnt[base + 0];
        if (base + 1 < n) v.y = cnt[base + 1];
        if (base + 2 < n) v.z = cnt[base + 2];
        if (base + 3 < n) v.w = cnt[base + 3];
    }
    int s = v.x + v.y + v.z + v.w;
    __shared__ int sh[256];
    sh[t] = s;
    __syncthreads();
    for (int o = 1; o < 256; o <<= 1) {
        int u = (t >= o) ? sh[t - o] : 0;
        __syncthreads();
        sh[t] += u;
        __syncthreads();
    }
    int excl = ((t == 0) ? 0 : sh[t - 1]) + bsum[blockIdx.x];
    int4 o4;
    o4.x = excl;
    o4.y = o4.x + v.x;
    o4.z = o4.y + v.y;
    o4.w = o4.z + v.z;
    if (base + 3 < n) {
        *(int4*)&offs[base] = o4;
        *(int4*)&cursor[base] = o4;
    } else {
        if (base + 0 < n) { offs[base + 0] = o4.x; cursor[base + 0] = o4.x; }
        if (base + 1 < n) { offs[base + 1] = o4.y; cursor[base + 1] = o4.y; }
        if (base + 2 < n) { offs[base + 2] = o4.z; cursor[base + 2] = o4.z; }
        if (base + 3 < n) { offs[base + 3] = o4.w; cursor[base + 3] = o4.w; }
    }
}

__global__ void fill_k(const int* __restrict__ src, const int* __restrict__ dst,
                       int* __restrict__ cursor, int* __restrict__ csr, int E) {
    int e = blockIdx.x * blockDim.x + threadIdx.x;
    if (e < E) {
        int p = atomicAdd(&cursor[dst[e]], 1);
        csr[p] = src[e];
    }
}

// ------------------------------------------- weight pre-split (bf16 hi/lo)
// Transposed bf16 hi/lo: Wt[n][k], slot stride 16384 elems.
// Slots: 2l = W_a[l], 2l+1 = W_b[l] (l=0..2), 6 = W_h1.
__global__ __launch_bounds__(256)
void wcvt_k(const float* __restrict__ Wa, const float* __restrict__ Wb,
            const float* __restrict__ Wh1,
            unsigned short* __restrict__ whi, unsigned short* __restrict__ wlo) {
    int id = blockIdx.x * 256 + threadIdx.x;
    float v; int dst;
    if (id < 49152) {                      // 3 x 128x128 W_a
        int l = id >> 14, e = id & 16383;
        v = Wa[id];
        int n = e & 127, k = e >> 7;
        dst = (2 * l) * 16384 + n * 128 + k;
    } else if (id < 98304) {               // 3 x 128x128 W_b
        int id2 = id - 49152;
        int l = id2 >> 14, e = id2 & 16383;
        v = Wb[id2];
        int n = e & 127, k = e >> 7;
        dst = (2 * l + 1) * 16384 + n * 128 + k;
    } else if (id < 106496) {              // 128x64 W_h1
        int e = id - 98304;
        v = Wh1[e];
        int n = e & 63, k = e >> 6;
        dst = 6 * 16384 + n * 128 + k;
    } else return;
    unsigned short hi = f2bf(v);
    whi[dst] = hi;
    wlo[dst] = f2bf(v - bf2f(hi));
}

// ------------------------------------------------------- fused GIN layer
// One block = 64 nodes. Phase 1: CSR gather-aggregate z into LDS (bf16
// hi/lo, split-precision). Phase 2: z @ W_a + b_a, ReLU (MFMA, 3-product
// split-bf16). Phase 3: u @ W_b + b_b, ReLU -> fp32 global (or, if HEAD,
// continue: phase 4 @ W_h1 + b_h1, ReLU; phase 5 @ W_h2 + b_h2 -> out).
// MFMA 16x16x32 layouts (verified R3): A[m=lane&15][k=quad*8+j],
// B = Wt[n=lane&15][k], C/D col=lane&15 row=quad*4+reg.
template <bool HEAD>
__global__ __launch_bounds__(256)
void fused_layer_k(const float* __restrict__ h_in,
                   const int* __restrict__ offs, const int* __restrict__ csr,
                   const float* __restrict__ eps, int layer,
                   const unsigned short* __restrict__ WAhi, const unsigned short* __restrict__ WAlo,
                   const float* __restrict__ ba,
                   const unsigned short* __restrict__ WBhi, const unsigned short* __restrict__ WBlo,
                   const float* __restrict__ bb,
                   const unsigned short* __restrict__ WHhi, const unsigned short* __restrict__ WHlo,
                   const float* __restrict__ bh1,
                   const float* __restrict__ W2, const float* __restrict__ b2,
                   float* __restrict__ outp) {
    __shared__ unsigned short Zhi[64 * 136];   // 17,408 B
    __shared__ unsigned short Zlo[64 * 136];
    const int t = threadIdx.x;
    const int wave = t >> 6, lane = t & 63;
    const int m = lane & 15, quad = lane >> 4;
    const int row0 = blockIdx.x * 64;
    const float sc = 1.0f + eps[layer];

    // ---------- phase 1: gather-aggregate -> LDS bf16 hi/lo
    {
        const int half = lane >> 5, l32 = lane & 31;
        const float4* __restrict__ h4 = (const float4*)h_in;
        for (int p8 = 0; p8 < 8; ++p8) {
            const int r = wave * 16 + p8 * 2 + half;
            const int node = row0 + r;
            float4 o = {0, 0, 0, 0};
            if (node < N_NODES) {
                const int beg = offs[node], end = offs[node + 1];
                float4 a0 = {0,0,0,0}, a1 = {0,0,0,0}, a2 = {0,0,0,0}, a3 = {0,0,0,0};
                int j = beg;
                for (; j + 4 <= end; j += 4) {
                    int s0 = csr[j], s1 = csr[j+1], s2 = csr[j+2], s3 = csr[j+3];
                    float4 v0 = h4[(size_t)s0 * 32 + l32];
                    float4 v1 = h4[(size_t)s1 * 32 + l32];
                    float4 v2 = h4[(size_t)s2 * 32 + l32];
                    float4 v3 = h4[(size_t)s3 * 32 + l32];
                    a0.x += v0.x; a0.y += v0.y; a0.z += v0.z; a0.w += v0.w;
                    a1.x += v1.x; a1.y += v1.y; a1.z += v1.z; a1.w += v1.w;
                    a2.x += v2.x; a2.y += v2.y; a2.z += v2.z; a2.w += v2.w;
                    a3.x += v3.x; a3.y += v3.y; a3.z += v3.z; a3.w += v3.w;
                }
                for (; j < end; ++j) {
                    float4 v = h4[(size_t)csr[j] * 32 + l32];
                    a0.x += v.x; a0.y += v.y; a0.z += v.z; a0.w += v.w;
                }
                float4 self = h4[(size_t)node * 32 + l32];
                o.x = sc * self.x + ((a0.x + a1.x) + (a2.x + a3.x));
                o.y = sc * self.y + ((a0.y + a1.y) + (a2.y + a3.y));
                o.z = sc * self.z + ((a0.z + a1.z) + (a2.z + a3.z));
                o.w = sc * self.w + ((a0.w + a1.w) + (a2.w + a3.w));
            }
            us4 hi, lo;
            hi.x = f2bf(o.x); lo.x = f2bf(o.x - bf2f(hi.x));
            hi.y = f2bf(o.y); lo.y = f2bf(o.y - bf2f(hi.y));
            hi.z = f2bf(o.z); lo.z = f2bf(o.z - bf2f(hi.z));
            hi.w = f2bf(o.w); lo.w = f2bf(o.w - bf2f(hi.w));
            *(us4*)&Zhi[r * 136 + l32 * 4] = hi;
            *(us4*)&Zlo[r * 136 + l32 * 4] = lo;
        }
    }

    // ---------- W_a fragments (cols: wave*32 + ct*16 + m)
    short8 wh[2][4], wl[2][4];
    for (int ct = 0; ct < 2; ++ct) {
        int n = wave * 32 + ct * 16 + m;
        for (int ks = 0; ks < 4; ++ks) {
            wh[ct][ks] = *(const short8*)&WAhi[n * 128 + ks * 32 + quad * 8];
            wl[ct][ks] = *(const short8*)&WAlo[n * 128 + ks * 32 + quad * 8];
        }
    }
    __syncthreads();

    // ---------- phase 2: z @ W_a
    f32x4 acc[4][2];
    for (int s = 0; s < 4; ++s)
        for (int ct = 0; ct < 2; ++ct) acc[s][ct] = (f32x4){0, 0, 0, 0};
    for (int s = 0; s < 4; ++s) {
        const int r = s * 16 + m;
        for (int ks = 0; ks < 4; ++ks) {
            short8 zh = *(const short8*)&Zhi[r * 136 + ks * 32 + quad * 8];
            short8 zl = *(const short8*)&Zlo[r * 136 + ks * 32 + quad * 8];
            for (int ct = 0; ct < 2; ++ct) {
                acc[s][ct] = __builtin_amdgcn_mfma_f32_16x16x32_bf16(zh, wh[ct][ks], acc[s][ct], 0, 0, 0);
                acc[s][ct] = __builtin_amdgcn_mfma_f32_16x16x32_bf16(zh, wl[ct][ks], acc[s][ct], 0, 0, 0);
                acc[s][ct] = __builtin_amdgcn_mfma_f32_16x16x32_bf16(zl, wh[ct][ks], acc[s][ct], 0, 0, 0);
            }
        }
    }

    // ---------- W_b fragments
    for (int ct = 0; ct < 2; ++ct) {
        int n = wave * 32 + ct * 16 + m;
        for (int ks = 0; ks < 4; ++ks) {
            wh[ct][ks] = *(const short8*)&WBhi[n * 128 + ks * 32 + quad * 8];
            wl[ct][ks] = *(const short8*)&WBlo[n * 128 + ks * 32 + quad * 8];
        }
    }
    __syncthreads();   // all z reads done; safe to overwrite LDS

    // ---------- u = relu(acc + ba) -> LDS bf16 hi/lo
    for (int s = 0; s < 4; ++s) {
        for (int ct = 0; ct < 2; ++ct) {
            int c = wave * 32 + ct * 16 + m;
            float bac = ba[c];
            for (int i = 0; i < 4; ++i) {
                int r = s * 16 + quad * 4 + i;
                float v = fmaxf(acc[s][ct][i] + bac, 0.0f);
                unsigned short hv = f2bf(v);
                Zhi[r * 136 + c] = hv;
                Zlo[r * 136 + c] = f2bf(v - bf2f(hv));
            }
        }
    }
    __syncthreads();

    // ---------- phase 3: u @ W_b
    for (int s = 0; s < 4; ++s)
        for (int ct = 0; ct < 2; ++ct) acc[s][ct] = (f32x4){0, 0, 0, 0};
    for (int s = 0; s < 4; ++s) {
        const int r = s * 16 + m;
        for (int ks = 0; ks < 4; ++ks) {
            short8 zh = *(const short8*)&Zhi[r * 136 + ks * 32 + quad * 8];
            short8 zl = *(const short8*)&Zlo[r * 136 + ks * 32 + quad * 8];
            for (int ct = 0; ct < 2; ++ct) {
                acc[s][ct] = __builtin_amdgcn_mfma_f32_16x16x32_bf16(zh, wh[ct][ks], acc[s][ct], 0, 0, 0);
                acc[s][ct] = __builtin_amdgcn_mfma_f32_16x16x32_bf16(zh, wl[ct][ks], acc[s][ct], 0, 0, 0);
                acc[s][ct] = __builtin_amdgcn_mfma_f32_16x16x32_bf16(zl, wh[ct][ks], acc[s][ct], 0, 0, 0);
            }
        }
    }

    if (!HEAD) {
        // ---------- h = relu(acc + bb) -> fp32 global
        for (int s = 0; s < 4; ++s) {
            for (int ct = 0; ct < 2; ++ct) {
                int c = wave * 32 + ct * 16 + m;
                float bbc = bb[c];
                for (int i = 0; i < 4; ++i) {
                    int row = row0 + s * 16 + quad * 4 + i;
                    if (row < N_NODES)
                        outp[(size_t)row * 128 + c] = fmaxf(acc[s][ct][i] + bbc, 0.0f);
                }
            }
        }
    } else {
        // ---------- W_h1 fragments (64 cols: wave*16 + m)
        short8 hh[4], hl[4];
        {
            int n = wave * 16 + m;
            for (int ks = 0; ks < 4; ++ks) {
                hh[ks] = *(const short8*)&WHhi[n * 128 + ks * 32 + quad * 8];
                hl[ks] = *(const short8*)&WHlo[n * 128 + ks * 32 + quad * 8];
            }
        }
        __syncthreads();   // all u reads done

        // ---------- h = relu(acc + bb) -> LDS bf16 hi/lo
        for (int s = 0; s < 4; ++s) {
            for (int ct = 0; ct < 2; ++ct) {
                int c = wave * 32 + ct * 16 + m;
                float bbc = bb[c];
                for (int i = 0; i < 4; ++i) {
                    int r = s * 16 + quad * 4 + i;
                    float v = fmaxf(acc[s][ct][i] + bbc, 0.0f);
                    unsigned short hv = f2bf(v);
                    Zhi[r * 136 + c] = hv;
                    Zlo[r * 136 + c] = f2bf(v - bf2f(hv));
                }
            }
        }
        __syncthreads();

        // ---------- phase 4: h @ W_h1 (128 -> 64)
        f32x4 a3[4];
        for (int s = 0; s < 4; ++s) a3[s] = (f32x4){0, 0, 0, 0};
        for (int s = 0; s < 4; ++s) {
            const int r = s * 16 + m;
            for (int ks = 0; ks < 4; ++ks) {
                short8 zh = *(const short8*)&Zhi[r * 136 + ks * 32 + quad * 8];
                short8 zl = *(const short8*)&Zlo[r * 136 + ks * 32 + quad * 8];
                a3[s] = __builtin_amdgcn_mfma_f32_16x16x32_bf16(zh, hh[ks], a3[s], 0, 0, 0);
                a3[s] = __builtin_amdgcn_mfma_f32_16x16x32_bf16(zh, hl[ks], a3[s], 0, 0, 0);
                a3[s] = __builtin_amdgcn_mfma_f32_16x16x32_bf16(zl, hh[ks], a3[s], 0, 0, 0);
            }
        }
        __syncthreads();   // phase-4 reads done; reuse LDS as fp32

        float* Hid = (float*)Zhi;   // 64 x 68 fp32 = 17,408 B (fits in Zhi)
        for (int s = 0; s < 4; ++s) {
            int c = wave * 16 + m;
            float bc = bh1[c];
            for (int i = 0; i < 4; ++i) {
                int r = s * 16 + quad * 4 + i;
                Hid[r * 68 + c] = fmaxf(a3[s][i] + bc, 0.0f);
            }
        }
        __syncthreads();

        // ---------- phase 5: hid @ W_h2 (64 -> 2) + b2 -> out
        if (t < 128) {
            int r = t >> 1, col = t & 1;
            float a = b2[col];
#pragma unroll
            for (int j = 0; j < 64; ++j) a += Hid[r * 68 + j] * W2[j * 2 + col];
            int node = row0 + r;
            if (node < N_NODES) outp[(size_t)node * 2 + col] = a;
        }
    }
}

// ------------------------------------------------------------------ launch

extern "C" void kernel_launch(void* const* d_in, const int* in_sizes, int n_in,
                              void* d_out, int out_size, void* d_ws, size_t ws_size,
                              hipStream_t stream) {
    const float* x    = (const float*)d_in[0];
    const int*   ei   = (const int*)d_in[1];
    const float* eps  = (const float*)d_in[2];
    const float* W_a  = (const float*)d_in[3];
    const float* b_a  = (const float*)d_in[4];
    const float* W_b  = (const float*)d_in[5];
    const float* b_b  = (const float*)d_in[6];
    const float* W_h1 = (const float*)d_in[7];
    const float* b_h1 = (const float*)d_in[8];
    const float* W_h2 = (const float*)d_in[9];
    const float* b_h2 = (const float*)d_in[10];
    float* out = (float*)d_out;

    const int N = N_NODES, E = N_EDGES;
    const int* src = ei;
    const int* dst = ei + E;

    char* ws = (char*)d_ws;
    size_t off = 0;
    auto carve = [&](size_t bytes) {
        char* p = ws + off;
        off = (off + bytes + 255) & ~(size_t)255;
        return p;
    };
    float* bufA   = (float*)carve((size_t)N * HID * sizeof(float));
    float* bufB   = (float*)carve((size_t)N * HID * sizeof(float));
    int*   cnt    = (int*)carve((size_t)N * sizeof(int));
    int*   offs   = (int*)carve((size_t)(N + 1) * sizeof(int));
    int*   cursor = (int*)carve((size_t)N * sizeof(int));
    int*   csr    = (int*)carve((size_t)E * sizeof(int));
    int*   bsum   = (int*)carve(64 * sizeof(int));
    unsigned short* whi = (unsigned short*)carve(7 * 16384 * sizeof(unsigned short));
    unsigned short* wlo = (unsigned short*)carve(7 * 16384 * sizeof(unsigned short));
    (void)ws_size;

    // ---- CSR build
    zero_k<<<(N + 255) / 256, 256, 0, stream>>>(cnt, N);
    count_k<<<(E + 255) / 256, 256, 0, stream>>>(dst, cnt, E);
    const int SB = (N + SCAN_CHUNK - 1) / SCAN_CHUNK;
    scan1_k<<<SB, 256, 0, stream>>>(cnt, bsum, N);
    scan2_k<<<1, 64, 0, stream>>>(bsum, offs, SB, N);
    scan3_k<<<SB, 256, 0, stream>>>(cnt, bsum, offs, cursor, N);
    fill_k<<<(E + 255) / 256, 256, 0, stream>>>(src, dst, cursor, csr, E);

    // ---- weight split/transpose
    wcvt_k<<<(106496 + 255) / 256, 256, 0, stream>>>(W_a, W_b, W_h1, whi, wlo);

    const int grid = (N + 63) / 64;
    #define WSLOT(s) (whi + (s) * 16384), (wlo + (s) * 16384)

    fused_layer_k<false><<<grid, 256, 0, stream>>>(
        x, offs, csr, eps, 0,
        WSLOT(0), b_a + 0 * 128, WSLOT(1), b_b + 0 * 128,
        (const unsigned short*)nullptr, (const unsigned short*)nullptr,
        (const float*)nullptr, (const float*)nullptr, (const float*)nullptr, bufA);
    fused_layer_k<false><<<grid, 256, 0, stream>>>(
        bufA, offs, csr, eps, 1,
        WSLOT(2), b_a + 1 * 128, WSLOT(3), b_b + 1 * 128,
        (const unsigned short*)nullptr, (const unsigned short*)nullptr,
        (const float*)nullptr, (const float*)nullptr, (const float*)nullptr, bufB);
    fused_layer_k<true><<<grid, 256, 0, stream>>>(
        bufB, offs, csr, eps, 2,
        WSLOT(4), b_a + 2 * 128, WSLOT(5), b_b + 2 * 128,
        WSLOT(6), b_h1, W_h2, b_h2, out);
}